// Round 10
// baseline (197.182 us; speedup 1.0000x reference)
//
#include <hip/hip_runtime.h>
#include <hip/hip_bf16.h>
#include <math.h>

#define T_ 2048
#define C_ 768
#define H_ 12
#define D_ 64
#define M_ 8192
#define QKV_N 2304

typedef short bf16x8 __attribute__((ext_vector_type(8)));
typedef float f32x4 __attribute__((ext_vector_type(4)));
typedef unsigned short u16;
typedef u16 u16x8 __attribute__((ext_vector_type(8)));
typedef u16 u16x4 __attribute__((ext_vector_type(4)));

// Static device scratch.
__device__ u16 g_xb [M_*C_];      // x in bf16 [M][K]
__device__ u16 g_wat[QKV_N*C_];   // W_attn^T bf16 [N][K]
__device__ u16 g_wpt[C_*C_];      // W_proj^T bf16 [N][K]
__device__ u16 g_q [M_*C_];       // [B*H][T][D]
__device__ u16 g_k [M_*C_];       // [B*H][T][D]
__device__ u16 g_vt[M_*C_];       // [B*H][D][T]
__device__ u16 g_y [M_*C_];       // [B*T][C]

__device__ __forceinline__ u16 f2bf(float f) {
    return __bfloat16_as_ushort(__float2bfloat16(f));
}
__device__ __forceinline__ f32x4 mfma16(bf16x8 a, bf16x8 b, f32x4 c) {
    return __builtin_amdgcn_mfma_f32_16x16x32_bf16(a, b, c, 0, 0, 0);
}
// async global->LDS, 16B per lane; LDS dest = wave-uniform base + lane*16 (HW).
__device__ __forceinline__ void gl16(const u16* g, u16* l) {
    __builtin_amdgcn_global_load_lds(
        (const __attribute__((address_space(1))) unsigned int*)g,
        (__attribute__((address_space(3))) unsigned int*)l, 16, 0, 0);
}
#define VMW(N)  asm volatile("s_waitcnt vmcnt(" #N ")" ::: "memory")
#define SBAR()  __builtin_amdgcn_s_barrier()
#define SFEN()  __builtin_amdgcn_sched_barrier(0)

// LDS tiles are [rows][64 u16] linear; data is chunk-swizzled: position chunk p
// at row r holds logical k-chunk (p ^ (r&7)). Read of logical chunk c:
__device__ __forceinline__ int ridx(int row, int chunk) {
    return row*64 + (((chunk) ^ (row & 7)) << 3);
}
// byte-level swizzle helper for sub-chunk writes (Ps): col in u16 units
__device__ __forceinline__ int swz(int row, int col) {
    return row*64 + ((((col >> 3) ^ (row & 7))) << 3) + (col & 7);
}

// ---------------------------------------------------------------------------
// Prep: x -> bf16
// ---------------------------------------------------------------------------
__global__ __launch_bounds__(256) void k_prep_x(const float* __restrict__ x)
{
    const int idx = blockIdx.x*256 + threadIdx.x;          // grid covers M*C/8
    float4 a = ((const float4*)x)[idx*2];
    float4 b = ((const float4*)x)[idx*2+1];
    u16x8 o;
    o[0]=f2bf(a.x); o[1]=f2bf(a.y); o[2]=f2bf(a.z); o[3]=f2bf(a.w);
    o[4]=f2bf(b.x); o[5]=f2bf(b.y); o[6]=f2bf(b.z); o[7]=f2bf(b.w);
    ((u16x8*)g_xb)[idx] = o;
}

// ---------------------------------------------------------------------------
// Prep: W [K][N] f32 -> W^T [N][K] bf16. One launch covers W_attn (x<36)
// and W_proj (x>=36).
// ---------------------------------------------------------------------------
__global__ __launch_bounds__(256) void k_prep_w(const float* __restrict__ Wa,
                                                const float* __restrict__ Wp)
{
    __shared__ u16 L[64][72];
    const int tid = threadIdx.x;
    const int bx  = blockIdx.x;
    const int which = (bx >= QKV_N/64);
    const float* src = which ? Wp : Wa;
    const int N = which ? C_ : QKV_N;
    u16* dst = which ? g_wpt : g_wat;
    const int n0 = (which ? bx - QKV_N/64 : bx) * 64;
    const int k0 = blockIdx.y * 64;

    const int r  = tid >> 2;            // k row 0..63
    const int c0 = (tid & 3) * 16;      // n seg
    const float* p = &src[(size_t)(k0 + r)*N + n0 + c0];
    float4 v[4];
    #pragma unroll
    for (int c = 0; c < 4; ++c) v[c] = ((const float4*)p)[c];
    const float* vf = (const float*)v;
    #pragma unroll
    for (int j = 0; j < 16; ++j) L[c0 + j][r] = f2bf(vf[j]);
    __syncthreads();
    const int nn = tid >> 2;
    const int s  = (tid & 3) * 16;
    *(u16x8*)&dst[(size_t)(n0+nn)*C_ + k0 + s]     = *(const u16x8*)&L[nn][s];
    *(u16x8*)&dst[(size_t)(n0+nn)*C_ + k0 + s + 8] = *(const u16x8*)&L[nn][s+8];
}

// ---------------------------------------------------------------------------
// Shared GEMM helpers: stage one 128x64 k-tile pair, compute one k-step.
// ---------------------------------------------------------------------------
__device__ __forceinline__ void stage2(const u16* a, const u16* b,
                                       u16* As_, u16* Bs_, int ko, int wid)
{
    #pragma unroll
    for (int i = 0; i < 4; ++i) {
        const int r = wid*32 + i*8;
        gl16(a + (size_t)i*8*C_ + ko, As_ + r*64);
        gl16(b + (size_t)i*8*C_ + ko, Bs_ + r*64);
    }
}
__device__ __forceinline__ void gemm_step(const u16* Asb, const u16* Bsb,
                                          f32x4 (&acc)[4][4],
                                          int wm, int wn, int l15, int lg)
{
    __builtin_amdgcn_s_setprio(1);
    #pragma unroll
    for (int kf = 0; kf < 2; ++kf) {
        bf16x8 bfr[4];
        #pragma unroll
        for (int nt = 0; nt < 4; ++nt)
            bfr[nt] = *(const bf16x8*)&Bsb[ridx(wn*64 + nt*16 + l15, kf*4 + lg)];
        #pragma unroll
        for (int mt = 0; mt < 4; ++mt) {
            bf16x8 afr = *(const bf16x8*)&Asb[ridx(wm*64 + mt*16 + l15, kf*4 + lg)];
            #pragma unroll
            for (int nt = 0; nt < 4; ++nt)
                acc[mt][nt] = mfma16(afr, bfr[nt], acc[mt][nt]);
        }
    }
    __builtin_amdgcn_s_setprio(0);
}

// ---------------------------------------------------------------------------
// Kernel 1: qkv = x @ W_attn + b_attn. 128x128 tile, BK=64, depth-2
// counted-vmcnt pipeline (T4): tiles k and k+1 in flight, vmcnt(8) waits.
// ---------------------------------------------------------------------------
__global__ __launch_bounds__(256) void k_qkv(const float* __restrict__ bias)
{
    __shared__ u16 As[2][128*64];
    __shared__ u16 Bs[2][128*64];

    const int tid  = threadIdx.x;
    const int lane = tid & 63;
    const int wid  = tid >> 6;
    const int l15  = lane & 15;
    const int lg   = lane >> 4;
    const int wm = wid >> 1, wn = wid & 1;
    const int m0 = blockIdx.x * 128;
    const int n0 = blockIdx.y * 128;

    const int srow8 = lane >> 3;              // 0..7 (row within 8-row issue)
    const int schk  = (lane & 7) ^ srow8;     // pre-swizzled source chunk

    f32x4 acc[4][4];
    #pragma unroll
    for (int i = 0; i < 4; ++i)
        #pragma unroll
        for (int j = 0; j < 4; ++j) acc[i][j] = (f32x4){0.f,0.f,0.f,0.f};

    const u16* xa = &g_xb [(size_t)(m0 + wid*32 + srow8)*C_ + (schk<<3)];
    const u16* wb = &g_wat[(size_t)(n0 + wid*32 + srow8)*C_ + (schk<<3)];

    // prologue: tiles 0 and 1 in flight (16 loads/wave)
    stage2(xa, wb, As[0], Bs[0], 0,  wid);
    stage2(xa, wb, As[1], Bs[1], 64, wid);

    int cur = 0;
    #pragma unroll 1
    for (int k = 0; k < 12; ++k) {
        if (k < 11) { VMW(8); } else { VMW(0); }   // tile k arrived
        SFEN();
        SBAR();                                    // all waves' tile-k loads done
        SFEN();
        gemm_step(As[cur], Bs[cur], acc, wm, wn, l15, lg);
        if (k < 10) {
            SBAR();                                // all waves done reading buf
            SFEN();
            stage2(xa, wb, As[cur], Bs[cur], (k+2)*64, wid);
        }
        cur ^= 1;
    }

    const int nb    = n0 + wn*64;
    const int which = nb / C_;
    const int h     = (nb % C_) / D_;
    const int mbase = m0 + wm*64;
    const int bb    = mbase >> 11;
    const int bh    = bb*H_ + h;
    float bv4[4];
    #pragma unroll
    for (int nt = 0; nt < 4; ++nt) bv4[nt] = bias[nb + nt*16 + l15];

    if (which == 2) {
        #pragma unroll
        for (int mt = 0; mt < 4; ++mt) {
            const int tb = (mbase + mt*16 + lg*4) & (T_-1);
            #pragma unroll
            for (int nt = 0; nt < 4; ++nt) {
                const int d = nt*16 + l15;
                u16x4 pk;
                #pragma unroll
                for (int r = 0; r < 4; ++r) pk[r] = f2bf(acc[mt][nt][r] + bv4[nt]);
                *(u16x4*)&g_vt[((size_t)bh*D_ + d)*T_ + tb] = pk;
            }
        }
    } else {
        u16* dst = which ? g_k : g_q;
        #pragma unroll
        for (int mt = 0; mt < 4; ++mt)
            #pragma unroll
            for (int r = 0; r < 4; ++r) {
                const int t = (mbase + mt*16 + lg*4 + r) & (T_-1);
                #pragma unroll
                for (int nt = 0; nt < 4; ++nt)
                    dst[((size_t)bh*T_ + t)*D_ + nt*16 + l15] = f2bf(acc[mt][nt][r] + bv4[nt]);
            }
    }
}

// ---------------------------------------------------------------------------
// Kernel 2: windowed flash attention on decayed logits, reverse iteration,
// fixed reference-max, depth-2 counted-vmcnt K/V pipeline (vmcnt(4)).
// ---------------------------------------------------------------------------
__global__ __launch_bounds__(256) void k_attn(const float* __restrict__ rates)
{
    __shared__ u16 Ks[2][64*64];
    __shared__ u16 Vt[2][64*64];
    __shared__ u16 Ps[4][16*64];

    const int tid  = threadIdx.x;
    const int lane = tid & 63;
    const int wid  = tid >> 6;
    const int l15  = lane & 15;
    const int lg   = lane >> 4;

    const int id  = blockIdx.x;
    const int bh  = (id & 7)*6 + ((id >> 3) % 6);
    const int qt  = 31 - ((id >> 3) / 6);      // big windows dispatch first
    const int h   = bh % H_;
    const int bb  = bh / H_;
    const float rate = rates[h];
    const float LOG2E  = 1.4426950408889634f;
    const float srate  = rate * LOG2E;
    const float sscale = 0.125f * LOG2E;

    const int i0  = qt * 64;
    const int thr = wid*16 + l15;              // q-row in block this lane owns
    const int ig  = i0 + thr;

    // decay window (tiles): keep while rate*delta < G(=16) + ln(1e8)
    const int wt = (int)(34.4f / (fmaxf(rate, 1e-8f) * 64.0f)) + 2;
    const int nT = min(qt + 1, wt);

    const u16* qb  = &g_q [(size_t)bh*T_*D_];
    const u16* kb  = &g_k [(size_t)bh*T_*D_];
    const u16* vtb = &g_vt[(size_t)bh*D_*T_];

    bf16x8 qf[2];
    qf[0] = *(const bf16x8*)&qb[(size_t)ig*D_ + lg*8];
    qf[1] = *(const bf16x8*)&qb[(size_t)ig*D_ + 32 + lg*8];

    float joff[16];
    #pragma unroll
    for (int t = 0; t < 4; ++t)
        #pragma unroll
        for (int r = 0; r < 4; ++r) joff[t*4+r] = srate * (float)(t*16 + lg*4 + r);

    f32x4 oAcc[4];
    #pragma unroll
    for (int n = 0; n < 4; ++n) oAcc[n] = (f32x4){0.f,0.f,0.f,0.f};
    float den = 0.f, mrow = 0.f;

    const int srow8 = lane >> 3;
    const int schk  = (lane & 7) ^ srow8;

    u16* PsW = &Ps[wid][0];

    // stage tile (j0) into buffer b: 2 K-issues + 2 V-issues per wave
    #define ATTN_STAGE(J0, B) do {                                             \
        _Pragma("unroll")                                                      \
        for (int i_ = 0; i_ < 2; ++i_) {                                       \
            const int r_ = wid*16 + i_*8;                                      \
            gl16(&kb [(size_t)((J0) + r_ + srow8)*D_ + (schk<<3)], &Ks[B][r_*64]); \
            gl16(&vtb[(size_t)(r_ + srow8)*T_ + (J0) + (schk<<3)], &Vt[B][r_*64]); \
        } } while (0)

    // prologue: tiles 0 (diag) and 1 in flight
    ATTN_STAGE(i0, 0);
    if (nT > 1) ATTN_STAGE(i0 - 64, 1);

    int cur = 0;
    #pragma unroll 1
    for (int tt = 0; tt < nT; ++tt) {
        const int j0 = i0 - tt*64;
        if (tt + 1 < nT) { VMW(4); } else { VMW(0); }   // tile tt arrived
        SFEN();
        SBAR();
        SFEN();

        const u16* Kc = Ks[cur];
        const u16* Vc = Vt[cur];

        // QK^T (swapped: A=K, B=Q -> lane owns q-row l15 across 16 j regs)
        __builtin_amdgcn_s_setprio(1);
        f32x4 sAcc[4];
        #pragma unroll
        for (int t = 0; t < 4; ++t) sAcc[t] = (f32x4){0.f,0.f,0.f,0.f};
        #pragma unroll
        for (int t = 0; t < 4; ++t)
            #pragma unroll
            for (int kf = 0; kf < 2; ++kf) {
                bf16x8 kfr = *(const bf16x8*)&Kc[ridx(t*16 + l15, kf*4 + lg)];
                sAcc[t] = mfma16(kfr, qf[kf], sAcc[t]);
            }
        __builtin_amdgcn_s_setprio(0);

        float e[16];
        if (tt == 0) {
            // diagonal tile: mask, take row max ONCE as the fixed reference
            const float sth = srate * (float)thr;
            float pv[16];
            float mx = -3e38f;
            #pragma unroll
            for (int t = 0; t < 4; ++t)
                #pragma unroll
                for (int r = 0; r < 4; ++r) {
                    const int jj = t*16 + lg*4 + r;
                    float v = fmaf(sAcc[t][r], sscale, joff[t*4+r] - sth);
                    if (jj > thr) v = -3e38f;
                    pv[t*4+r] = v;
                    mx = fmaxf(mx, v);
                }
            mx = fmaxf(mx, __shfl_xor(mx, 16, 64));
            mx = fmaxf(mx, __shfl_xor(mx, 32, 64));
            mrow = mx;
            #pragma unroll
            for (int i = 0; i < 16; ++i) {
                e[i] = __builtin_amdgcn_exp2f(pv[i] - mx);
                den += e[i];
            }
        } else {
            // fast path: no mask, no max tracking; fold m into the constant
            const float c0m = fmaf(srate, (float)(j0 - ig), -mrow);
            #pragma unroll
            for (int t = 0; t < 4; ++t)
                #pragma unroll
                for (int r = 0; r < 4; ++r) {
                    const float v = fmaf(sAcc[t][r], sscale, c0m + joff[t*4+r]);
                    const float p = __builtin_amdgcn_exp2f(v);
                    e[t*4+r] = p;
                    den += p;
                }
        }

        // pack P (bf16) into wave-private LDS rows
        #pragma unroll
        for (int t = 0; t < 4; ++t) {
            u16x4 pk = { f2bf(e[t*4]), f2bf(e[t*4+1]), f2bf(e[t*4+2]), f2bf(e[t*4+3]) };
            *(u16x4*)&PsW[swz(l15, t*16 + lg*4)] = pk;
        }

        // PV
        __builtin_amdgcn_s_setprio(1);
        #pragma unroll
        for (int kf = 0; kf < 2; ++kf) {
            bf16x8 pa = *(const bf16x8*)&PsW[ridx(l15, kf*4 + lg)];
            #pragma unroll
            for (int n = 0; n < 4; ++n) {
                bf16x8 vf = *(const bf16x8*)&Vc[ridx(n*16 + l15, kf*4 + lg)];
                oAcc[n] = mfma16(pa, vf, oAcc[n]);
            }
        }
        __builtin_amdgcn_s_setprio(0);

        if (tt + 2 < nT) {                     // re-stage freed buffer
            SBAR();
            SFEN();
            ATTN_STAGE(j0 - 128, cur);
        }
        cur ^= 1;
    }

    // single end-of-loop reduction + normalize + store
    den += __shfl_xor(den, 16, 64);
    den += __shfl_xor(den, 32, 64);
    const float inv = 1.f / den;
    float ivr[4];
    #pragma unroll
    for (int r = 0; r < 4; ++r) ivr[r] = __shfl(inv, lg*4 + r, 64);
    #pragma unroll
    for (int r = 0; r < 4; ++r) {
        const int row = i0 + wid*16 + lg*4 + r;
        #pragma unroll
        for (int n = 0; n < 4; ++n)
            g_y[(size_t)(bb*T_ + row)*C_ + h*D_ + n*16 + l15] = f2bf(oAcc[n][r] * ivr[r]);
    }
}

// ---------------------------------------------------------------------------
// Kernel 3: out = y @ W_proj + b_proj (same pipeline, fp32 out)
// ---------------------------------------------------------------------------
__global__ __launch_bounds__(256) void k_proj(const float* __restrict__ bias,
                                              float* __restrict__ out)
{
    __shared__ u16 As[2][128*64];
    __shared__ u16 Bs[2][128*64];

    const int tid  = threadIdx.x;
    const int lane = tid & 63;
    const int wid  = tid >> 6;
    const int l15  = lane & 15;
    const int lg   = lane >> 4;
    const int wm = wid >> 1, wn = wid & 1;
    const int m0 = blockIdx.x * 128;
    const int n0 = blockIdx.y * 128;

    const int srow8 = lane >> 3;
    const int schk  = (lane & 7) ^ srow8;

    f32x4 acc[4][4];
    #pragma unroll
    for (int i = 0; i < 4; ++i)
        #pragma unroll
        for (int j = 0; j < 4; ++j) acc[i][j] = (f32x4){0.f,0.f,0.f,0.f};

    const u16* ya = &g_y  [(size_t)(m0 + wid*32 + srow8)*C_ + (schk<<3)];
    const u16* wb = &g_wpt[(size_t)(n0 + wid*32 + srow8)*C_ + (schk<<3)];

    stage2(ya, wb, As[0], Bs[0], 0,  wid);
    stage2(ya, wb, As[1], Bs[1], 64, wid);

    int cur = 0;
    #pragma unroll 1
    for (int k = 0; k < 12; ++k) {
        if (k < 11) { VMW(8); } else { VMW(0); }
        SFEN();
        SBAR();
        SFEN();
        gemm_step(As[cur], Bs[cur], acc, wm, wn, l15, lg);
        if (k < 10) {
            SBAR();
            SFEN();
            stage2(ya, wb, As[cur], Bs[cur], (k+2)*64, wid);
        }
        cur ^= 1;
    }

    float bv4[4];
    #pragma unroll
    for (int nt = 0; nt < 4; ++nt) bv4[nt] = bias[n0 + wn*64 + nt*16 + l15];
    #pragma unroll
    for (int mt = 0; mt < 4; ++mt)
        #pragma unroll
        for (int r = 0; r < 4; ++r) {
            const int m = m0 + wm*64 + mt*16 + lg*4 + r;
            #pragma unroll
            for (int nt = 0; nt < 4; ++nt)
                out[(size_t)m*C_ + n0 + wn*64 + nt*16 + l15] = acc[mt][nt][r] + bv4[nt];
        }
}

extern "C" void kernel_launch(void* const* d_in, const int* in_sizes, int n_in,
                              void* d_out, int out_size, void* d_ws, size_t ws_size,
                              hipStream_t stream) {
    (void)in_sizes; (void)n_in; (void)d_ws; (void)ws_size; (void)out_size;
    const float* x      = (const float*)d_in[0];
    const float* W_attn = (const float*)d_in[1];
    const float* b_attn = (const float*)d_in[2];
    const float* W_proj = (const float*)d_in[3];
    const float* b_proj = (const float*)d_in[4];
    const float* rates  = (const float*)d_in[5];

    hipLaunchKernelGGL(k_prep_x, dim3(M_*C_/8/256), dim3(256), 0, stream, x);
    hipLaunchKernelGGL(k_prep_w, dim3(QKV_N/64 + C_/64, C_/64), dim3(256), 0, stream, W_attn, W_proj);
    hipLaunchKernelGGL(k_qkv,  dim3(M_/128, QKV_N/128), dim3(256), 0, stream, b_attn);
    hipLaunchKernelGGL(k_attn, dim3(1536),              dim3(256), 0, stream, rates);
    hipLaunchKernelGGL(k_proj, dim3(M_/128, C_/128),    dim3(256), 0, stream, b_proj, (float*)d_out);
}